// Round 1
// baseline (42.458 us; speedup 1.0000x reference)
//
#include <hip/hip_runtime.h>

// LengthRegulator: B=16, T=512, D=384, max_length=4096.
// out[b,f,:] = x[b, searchsorted(cum_b, f, 'right') clamped to T-1, :] * (f < total_b)
// d_out = [out | mel_pos] concatenated, identical copies.

constexpr int B  = 16;
constexpr int T  = 512;
constexpr int D  = 384;
constexpr int ML = 4096;
constexpr int QPF = D / 4;          // 96 float4 per frame row
constexpr int FPB = 16;             // frames per block in expand kernel
constexpr long long OUT_ELEMS = (long long)B * ML * D;   // one output's element count

// ---- Kernel 1: per-batch inclusive scan of duration (T=512) ----
__global__ void lr_scan_kernel(const int* __restrict__ dur, int* __restrict__ cum) {
    __shared__ int s[T];
    const int b = blockIdx.x;
    const int t = threadIdx.x;
    s[t] = dur[b * T + t];
    __syncthreads();
    #pragma unroll
    for (int off = 1; off < T; off <<= 1) {
        int v = (t >= off) ? s[t - off] : 0;
        __syncthreads();
        s[t] += v;
        __syncthreads();
    }
    cum[b * T + t] = s[t];
}

// ---- Kernel 2: expand/gather. One block handles FPB frames of one batch. ----
__global__ __launch_bounds__(256)
void lr_expand_kernel(const float4* __restrict__ x, const int* __restrict__ cum,
                      float4* __restrict__ out) {
    __shared__ int sidx[FPB];
    const int blocksPerB = ML / FPB;                    // 256
    const int b  = blockIdx.x / blocksPerB;
    const int f0 = (blockIdx.x % blocksPerB) * FPB;
    const int* __restrict__ c = cum + b * T;
    const int t = threadIdx.x;

    if (t < FPB) {
        const int f = f0 + t;
        const int total = c[T - 1];
        if (f >= total) {
            sidx[t] = -1;                               // masked -> zero row
        } else {
            // searchsorted(c, f, side='right'): first i with c[i] > f
            int lo = 0, hi = T;
            while (lo < hi) {
                int mid = (lo + hi) >> 1;
                if (c[mid] <= f) lo = mid + 1; else hi = mid;
            }
            sidx[t] = (lo < T - 1) ? lo : (T - 1);
        }
    }
    __syncthreads();

    const float4 zero = make_float4(0.f, 0.f, 0.f, 0.f);
    float4* __restrict__ out0 = out;
    float4* __restrict__ out1 = out + OUT_ELEMS / 4;    // mel_pos copy

    #pragma unroll
    for (int j = t; j < FPB * QPF; j += 256) {
        const int fl  = j / QPF;
        const int q   = j - fl * QPF;
        const int idx = sidx[fl];
        const float4 v = (idx >= 0) ? x[((size_t)(b * T + idx)) * QPF + q] : zero;
        const size_t o = ((size_t)(b * ML + f0 + fl)) * QPF + q;
        out0[o] = v;
        out1[o] = v;
    }
}

extern "C" void kernel_launch(void* const* d_in, const int* in_sizes, int n_in,
                              void* d_out, int out_size, void* d_ws, size_t ws_size,
                              hipStream_t stream) {
    const float* x  = (const float*)d_in[0];
    const int* dur  = (const int*)d_in[1];   // JAX x64 disabled -> int32 on device
    // d_in[2] = max_length scalar (4096) — shapes are fixed by setup_inputs.

    int* cum = (int*)d_ws;                   // B*T ints = 32 KiB scratch

    lr_scan_kernel<<<B, T, 0, stream>>>(dur, cum);
    lr_expand_kernel<<<B * (ML / FPB), 256, 0, stream>>>(
        (const float4*)x, cum, (float4*)d_out);
}

// Round 2
// 34.077 us; speedup vs baseline: 1.2460x; 1.2460x over previous
//
#include <hip/hip_runtime.h>

// LengthRegulator fused: B=16, T=512, D=384, max_length=4096.
// out[b,f,:] = x[b, min(searchsorted(cum_b, f, 'right'), T-1), :] * (f < total_b)
// d_out = [out | mel_pos], two identical fp32 copies.
//
// Single kernel: each block re-computes its batch's 512-elem duration cumsum
// (2 KB, L2-hot) with a wave-shuffle scan, binary-searches LDS, then streams
// FPB frames x 2 copies with coalesced float4 stores.

constexpr int B   = 16;
constexpr int T   = 512;
constexpr int D   = 384;
constexpr int ML  = 4096;
constexpr int QPF = D / 4;              // 96 float4 per frame row
constexpr int FPB = 32;                 // frames per block
constexpr int NBLK = B * (ML / FPB);    // 2048 blocks
constexpr long long OUT_Q = (long long)B * ML * QPF;  // float4 per output copy

typedef float vfloat4 __attribute__((ext_vector_type(4)));

__global__ __launch_bounds__(256)
void lr_fused_kernel(const vfloat4* __restrict__ x, const int* __restrict__ dur,
                     vfloat4* __restrict__ out) {
    __shared__ int cum_s[T];
    __shared__ int wsum[4];
    __shared__ int sidx[FPB];

    const int blocksPerB = ML / FPB;            // 128
    const int b    = blockIdx.x / blocksPerB;
    const int f0   = (blockIdx.x % blocksPerB) * FPB;
    const int t    = threadIdx.x;
    const int lane = t & 63;
    const int wid  = t >> 6;

    // ---- in-block inclusive scan of duration[b, :] (512 elems, 2/thread) ----
    const int d0 = dur[b * T + 2 * t];
    const int d1 = dur[b * T + 2 * t + 1];
    int s = d0 + d1;
    #pragma unroll
    for (int off = 1; off < 64; off <<= 1) {
        int v = __shfl_up(s, off, 64);
        if (lane >= off) s += v;
    }
    if (lane == 63) wsum[wid] = s;
    __syncthreads();
    #pragma unroll
    for (int w = 0; w < 3; ++w)
        if (w < wid) s += wsum[w];
    cum_s[2 * t]     = s - d1;
    cum_s[2 * t + 1] = s;
    __syncthreads();

    const int total = cum_s[T - 1];

    if (t < FPB) {
        const int f = f0 + t;
        if (f >= total) {
            sidx[t] = -1;                       // masked -> zero row
        } else {
            // searchsorted(cum, f, 'right'): first i with cum[i] > f
            int lo = 0, hi = T;
            while (lo < hi) {
                int mid = (lo + hi) >> 1;
                if (cum_s[mid] <= f) lo = mid + 1; else hi = mid;
            }
            sidx[t] = (lo < T - 1) ? lo : (T - 1);
        }
    }
    __syncthreads();

    const vfloat4 zero = {0.f, 0.f, 0.f, 0.f};
    vfloat4* __restrict__ out1 = out + OUT_Q;   // mel_pos copy

    #pragma unroll
    for (int j = t; j < FPB * QPF; j += 256) {
        const int fl  = j / QPF;
        const int q   = j - fl * QPF;
        const int idx = sidx[fl];
        vfloat4 v = zero;
        if (idx >= 0) v = x[(size_t)(b * T + idx) * QPF + q];
        const size_t o = (size_t)(b * ML + f0 + fl) * QPF + q;
        out[o]  = v;
        out1[o] = v;
    }
}

extern "C" void kernel_launch(void* const* d_in, const int* in_sizes, int n_in,
                              void* d_out, int out_size, void* d_ws, size_t ws_size,
                              hipStream_t stream) {
    const float* x = (const float*)d_in[0];
    const int* dur = (const int*)d_in[1];   // JAX x64 disabled -> int32 on device
    // d_in[2] = max_length scalar (4096) — shapes fixed by setup_inputs.

    lr_fused_kernel<<<NBLK, 256, 0, stream>>>(
        (const vfloat4*)x, dur, (vfloat4*)d_out);
}